// Round 6
// baseline (578.809 us; speedup 1.0000x reference)
//
#include <hip/hip_runtime.h>
#include <hip/hip_fp16.h>
#include <math.h>

#define N_NODES 100000
#define N_EDGES 1000000
#define F_IN    128
#define HID     64
#define HEADS   4
#define NCLS    4
#define SCAN_BLK 98   // ceil(N_NODES / 1024)
#define GEMM_NT 5     // node-tiles per block in MFMA GEMMs (80 nodes/block)

typedef _Float16 half8 __attribute__((ext_vector_type(8)));
typedef _Float16 half4v __attribute__((ext_vector_type(4)));
typedef _Float16 fp16x2 __attribute__((ext_vector_type(2)));
typedef float f32x4 __attribute__((ext_vector_type(4)));
typedef float f32x2 __attribute__((ext_vector_type(2)));

// ---------------- helpers ----------------
__device__ __forceinline__ float wsum(float v) {
#pragma unroll
  for (int o = 32; o > 0; o >>= 1) v += __shfl_xor(v, o, 64);
  return v;
}
struct Half4 { __half2 a, b; };
__device__ __forceinline__ __half2 absh2(__half2 v) {
  unsigned u; __builtin_memcpy(&u, &v, 4);
  u &= 0x7FFF7FFFu;
  __half2 r; __builtin_memcpy(&r, &u, 4);
  return r;
}
__device__ __forceinline__ float fdot2f(__half2 a, __half2 b, float c) {
#if defined(__has_builtin) && __has_builtin(__builtin_amdgcn_fdot2)
  fp16x2 av, bv;
  __builtin_memcpy(&av, &a, 4); __builtin_memcpy(&bv, &b, 4);
  return __builtin_amdgcn_fdot2(av, bv, c, false);
#else
  float2 af = __half22float2(a), bf = __half22float2(b);
  return c + af.x * bf.x + af.y * bf.y;
#endif
}
__device__ __forceinline__ float fexp2(float x) {
#if defined(__has_builtin) && __has_builtin(__builtin_amdgcn_exp2f)
  return __builtin_amdgcn_exp2f(x);
#else
  return exp2f(x);
#endif
}
__device__ __forceinline__ __half2 h2of4(half4v v, int p) {
  fp16x2 t; t[0] = v[2 * p]; t[1] = v[2 * p + 1];
  __half2 r; __builtin_memcpy(&r, &t, 4);
  return r;
}
// score partial over this lane's 4 feats with leaky folded into att:
// score = (0.6*att*log2e)·t + (0.4*att*log2e)·|t|,  t = A + R  (base-2 exponent)
__device__ __forceinline__ float edge_score(half4v A, half4v R,
                                            __half2 p0, __half2 p1,
                                            __half2 q0, __half2 q1) {
  __half2 t0 = __hadd2(h2of4(A, 0), h2of4(R, 0));
  __half2 t1 = __hadd2(h2of4(A, 1), h2of4(R, 1));
  float s = fdot2f(t0, p0, 0.f);
  s = fdot2f(t1, p1, s);
  s = fdot2f(absh2(t0), q0, s);
  s = fdot2f(absh2(t1), q1, s);
  return s;
}
__device__ __forceinline__ float reduce16(float q) {
  q += __shfl_xor(q, 1); q += __shfl_xor(q, 2);
  q += __shfl_xor(q, 4); q += __shfl_xor(q, 8);
  return q;
}
// wave-uniform node id -> SGPR (row_ptr/csr reads become scalar loads)
__device__ __forceinline__ int wave_node() {
  return __builtin_amdgcn_readfirstlane(blockIdx.x * 4 + (threadIdx.x >> 6));
}

// ---------------- CSR build (by dst) ----------------
__global__ void k_hist(const int* __restrict__ dst, int* __restrict__ cnt) {
  int e = blockIdx.x * 256 + threadIdx.x;
  if (e < N_EDGES) atomicAdd(&cnt[dst[e]], 1);
}
__global__ __launch_bounds__(256) void k_scan1(const int* __restrict__ cnt,
                                               int* __restrict__ partial,
                                               int* __restrict__ bsum) {
  __shared__ int lds[256];
  int t = threadIdx.x;
  int base = blockIdx.x * 1024 + t * 4;
  int v0 = (base + 0 < N_NODES) ? cnt[base + 0] : 0;
  int v1 = (base + 1 < N_NODES) ? cnt[base + 1] : 0;
  int v2 = (base + 2 < N_NODES) ? cnt[base + 2] : 0;
  int v3 = (base + 3 < N_NODES) ? cnt[base + 3] : 0;
  int s = v0 + v1 + v2 + v3;
  lds[t] = s;
  __syncthreads();
  for (int o = 1; o < 256; o <<= 1) {
    int x = (t >= o) ? lds[t - o] : 0;
    __syncthreads();
    lds[t] += x;
    __syncthreads();
  }
  int excl = lds[t] - s;
  if (base + 0 < N_NODES) partial[base + 0] = excl;
  if (base + 1 < N_NODES) partial[base + 1] = excl + v0;
  if (base + 2 < N_NODES) partial[base + 2] = excl + v0 + v1;
  if (base + 3 < N_NODES) partial[base + 3] = excl + v0 + v1 + v2;
  if (t == 255) bsum[blockIdx.x] = lds[255];
}
// scan of bsum folded in: every block redundantly scans the 98 block-sums.
__global__ __launch_bounds__(256) void k_scan3(const int* __restrict__ partial,
                                               const int* __restrict__ bsum,
                                               int* __restrict__ row_ptr,
                                               int* __restrict__ cursor) {
  __shared__ int ex[128];
  int t = threadIdx.x;
  int orig = 0;
  if (t < 128) {
    orig = (t < SCAN_BLK) ? bsum[t] : 0;
    ex[t] = orig;
  }
  __syncthreads();
  for (int o = 1; o < 128; o <<= 1) {
    int x = (t < 128 && t >= o) ? ex[t - o] : 0;
    __syncthreads();
    if (t < 128) ex[t] += x;
    __syncthreads();
  }
  if (t < 128) ex[t] -= orig;  // exclusive
  __syncthreads();
  int i = blockIdx.x * 256 + t;
  if (i < N_NODES) {
    int v = partial[i] + ex[i >> 10];
    row_ptr[i] = v;
    cursor[i] = v;
  }
  if (i == 0) row_ptr[N_NODES] = N_EDGES;
}
__global__ void k_fill(const int* __restrict__ src, const int* __restrict__ dst,
                       const float* __restrict__ ew, int* __restrict__ cursor,
                       int* __restrict__ csr_src, float* __restrict__ csr_w) {
  int e = blockIdx.x * 256 + threadIdx.x;
  if (e >= N_EDGES) return;
  int d = dst[e];
  int p = atomicAdd(&cursor[d], 1);
  csr_src[p] = src[e];
  csr_w[p] = ew[e];
}

// ---------------- MFMA GEMM 1: [xw16|xp16] = x @ [gcn_W|proj_W]  (K=128, N=128) --
__global__ __launch_bounds__(512) void k_in_gemm_mfma(
    const float* __restrict__ x, const float* __restrict__ gcn_W,
    const float* __restrict__ proj_W, const float* __restrict__ proj_b,
    __half* __restrict__ xw16, __half* __restrict__ xp16) {
  __shared__ __half at[16 * 136];
  int t = threadIdx.x;
  int w = t >> 6, lane = t & 63;
  int m = lane & 15, q = lane >> 4;
  int ncol = w * 16 + m;                 // 0..127
  const float* W = (ncol < 64) ? gcn_W : proj_W;
  int nc = (ncol < 64) ? ncol : ncol - 64;
  half8 bf[4];
#pragma unroll
  for (int ch = 0; ch < 4; ++ch) {
    int kb = ch * 32 + q * 8;
#pragma unroll
    for (int j = 0; j < 8; ++j)
      bf[ch][j] = (_Float16)W[(kb + j) * 64 + nc];
  }
  float pb = (ncol >= 64) ? proj_b[nc] : 0.f;
  int nb0 = blockIdx.x * (16 * GEMM_NT);
  for (int nt = 0; nt < GEMM_NT; ++nt) {
    int nb = nb0 + nt * 16;
    {
      int row = t >> 5, col = (t & 31) * 4;
      float4 v = *reinterpret_cast<const float4*>(x + (size_t)(nb + row) * F_IN + col);
      __half2* d = reinterpret_cast<__half2*>(&at[row * 136 + col]);
      d[0] = __floats2half2_rn(v.x, v.y);
      d[1] = __floats2half2_rn(v.z, v.w);
    }
    __syncthreads();
    f32x4 acc = {0.f, 0.f, 0.f, 0.f};
#pragma unroll
    for (int ch = 0; ch < 4; ++ch) {
      half8 af = *reinterpret_cast<const half8*>(&at[m * 136 + ch * 32 + q * 8]);
      acc = __builtin_amdgcn_mfma_f32_16x16x32_f16(af, bf[ch], acc, 0, 0, 0);
    }
    if (ncol < 64) {
#pragma unroll
      for (int r = 0; r < 4; ++r)
        xw16[(size_t)(nb + q * 4 + r) * HID + nc] = __float2half(acc[r]);
    } else {
#pragma unroll
      for (int r = 0; r < 4; ++r)
        xp16[(size_t)(nb + q * 4 + r) * HID + nc] = __float2half(acc[r] + pb);
    }
    __syncthreads();
  }
}

// ---------------- GCN: deg/dinv from CSR (no atomics) ----------------
__global__ void k_deg(const int* __restrict__ row_ptr, const float* __restrict__ csr_w,
                      float* __restrict__ dinv) {
  int n = blockIdx.x * 256 + threadIdx.x;
  if (n >= N_NODES) return;
  float deg = 1.0f;  // self-loop weight
  int end = row_ptr[n + 1];
  for (int i = row_ptr[n]; i < end; ++i) deg += csr_w[i];
  dinv[n] = rsqrtf(deg);  // deg >= 1 always
}

// pull-gather + LN + relu + residual, one wave per node (n in SGPR), 8x MLP
__global__ __launch_bounds__(256) void k_gcn_fused(
    const int* __restrict__ row_ptr, const int* __restrict__ csr_src,
    const float* __restrict__ csr_w, const float* __restrict__ dinv,
    const __half* __restrict__ xw16, const __half* __restrict__ xp16,
    const float* __restrict__ gcn_b, const float* __restrict__ g,
    const float* __restrict__ bb, __half* __restrict__ h_init16) {
  int n = wave_node();
  int lane = threadIdx.x & 63;
  float di = dinv[n];
  float acc = di * di * __half2float(xw16[(size_t)n * HID + lane]);  // self loop
  float acc2 = 0.f;
  int beg = row_ptr[n], end = row_ptr[n + 1];
  int i = beg;
  for (; i + 8 <= end; i += 8) {
    int s0 = __builtin_amdgcn_readfirstlane(csr_src[i]);
    int s1 = __builtin_amdgcn_readfirstlane(csr_src[i + 1]);
    int s2 = __builtin_amdgcn_readfirstlane(csr_src[i + 2]);
    int s3 = __builtin_amdgcn_readfirstlane(csr_src[i + 3]);
    int s4 = __builtin_amdgcn_readfirstlane(csr_src[i + 4]);
    int s5 = __builtin_amdgcn_readfirstlane(csr_src[i + 5]);
    int s6 = __builtin_amdgcn_readfirstlane(csr_src[i + 6]);
    int s7 = __builtin_amdgcn_readfirstlane(csr_src[i + 7]);
    float nrm0 = dinv[s0] * csr_w[i] * di;
    float nrm1 = dinv[s1] * csr_w[i + 1] * di;
    float nrm2 = dinv[s2] * csr_w[i + 2] * di;
    float nrm3 = dinv[s3] * csr_w[i + 3] * di;
    float nrm4 = dinv[s4] * csr_w[i + 4] * di;
    float nrm5 = dinv[s5] * csr_w[i + 5] * di;
    float nrm6 = dinv[s6] * csr_w[i + 6] * di;
    float nrm7 = dinv[s7] * csr_w[i + 7] * di;
    float v0 = __half2float(xw16[(size_t)s0 * HID + lane]);
    float v1 = __half2float(xw16[(size_t)s1 * HID + lane]);
    float v2 = __half2float(xw16[(size_t)s2 * HID + lane]);
    float v3 = __half2float(xw16[(size_t)s3 * HID + lane]);
    float v4 = __half2float(xw16[(size_t)s4 * HID + lane]);
    float v5 = __half2float(xw16[(size_t)s5 * HID + lane]);
    float v6 = __half2float(xw16[(size_t)s6 * HID + lane]);
    float v7 = __half2float(xw16[(size_t)s7 * HID + lane]);
    acc  += nrm0 * v0 + nrm1 * v1 + nrm2 * v2 + nrm3 * v3;
    acc2 += nrm4 * v4 + nrm5 * v5 + nrm6 * v6 + nrm7 * v7;
  }
  for (; i + 4 <= end; i += 4) {
    int s0 = __builtin_amdgcn_readfirstlane(csr_src[i]);
    int s1 = __builtin_amdgcn_readfirstlane(csr_src[i + 1]);
    int s2 = __builtin_amdgcn_readfirstlane(csr_src[i + 2]);
    int s3 = __builtin_amdgcn_readfirstlane(csr_src[i + 3]);
    float nrm0 = dinv[s0] * csr_w[i] * di;
    float nrm1 = dinv[s1] * csr_w[i + 1] * di;
    float nrm2 = dinv[s2] * csr_w[i + 2] * di;
    float nrm3 = dinv[s3] * csr_w[i + 3] * di;
    float v0 = __half2float(xw16[(size_t)s0 * HID + lane]);
    float v1 = __half2float(xw16[(size_t)s1 * HID + lane]);
    float v2 = __half2float(xw16[(size_t)s2 * HID + lane]);
    float v3 = __half2float(xw16[(size_t)s3 * HID + lane]);
    acc += nrm0 * v0 + nrm1 * v1 + nrm2 * v2 + nrm3 * v3;
  }
  for (; i < end; ++i) {
    int s = __builtin_amdgcn_readfirstlane(csr_src[i]);
    float nrm = dinv[s] * csr_w[i] * di;
    acc += nrm * __half2float(xw16[(size_t)s * HID + lane]);
  }
  float v = acc + acc2 + gcn_b[lane];
  float mu = wsum(v) * (1.f / HID);
  float dv = v - mu;
  float var = wsum(dv * dv) * (1.f / HID);
  float h = dv * rsqrtf(var + 1e-5f) * g[lane] + bb[lane];
  h = h > 0.f ? h : 0.f;
  h_init16[(size_t)n * HID + lane] =
      __float2half(h + __half2float(xp16[(size_t)n * HID + lane]));
}

// ---------------- MFMA GEMM 2: [xl|xr] = h16 @ [Wl|Wr]  (K=64, N=512) ----------
__global__ __launch_bounds__(512) void k_gat_gemm_mfma(
    const __half* __restrict__ h16, const float* __restrict__ Wl,
    const float* __restrict__ Wr, __half* __restrict__ xl, __half* __restrict__ xr) {
  __shared__ __half at[16 * 72];
  int t = threadIdx.x;
  int w = t >> 6, lane = t & 63;
  int m = lane & 15, q = lane >> 4;
  half8 bf[4][2];
#pragma unroll
  for (int tt = 0; tt < 4; ++tt) {
    int c = w * 16 + tt * 128 + m;          // 0..511
    const float* W = (c < 256) ? Wl : Wr;
    int nc = (c < 256) ? c : c - 256;
#pragma unroll
    for (int ch = 0; ch < 2; ++ch) {
      int kb = ch * 32 + q * 8;
#pragma unroll
      for (int j = 0; j < 8; ++j)
        bf[tt][ch][j] = (_Float16)W[(kb + j) * 256 + nc];
    }
  }
  int nb0 = blockIdx.x * (16 * GEMM_NT);
  for (int nt = 0; nt < GEMM_NT; ++nt) {
    int nb = nb0 + nt * 16;
    {
      int row = t >> 5, col = (t & 31) * 2;
      *reinterpret_cast<__half2*>(&at[row * 72 + col]) =
          *reinterpret_cast<const __half2*>(h16 + (size_t)(nb + row) * HID + col);
    }
    __syncthreads();
    half8 a0 = *reinterpret_cast<const half8*>(&at[m * 72 + q * 8]);
    half8 a1 = *reinterpret_cast<const half8*>(&at[m * 72 + 32 + q * 8]);
#pragma unroll
    for (int tt = 0; tt < 4; ++tt) {
      f32x4 acc = {0.f, 0.f, 0.f, 0.f};
      acc = __builtin_amdgcn_mfma_f32_16x16x32_f16(a0, bf[tt][0], acc, 0, 0, 0);
      acc = __builtin_amdgcn_mfma_f32_16x16x32_f16(a1, bf[tt][1], acc, 0, 0, 0);
      int c = w * 16 + tt * 128 + m;
      __half* out = (c < 256) ? (xl + c) : (xr + (c - 256));
#pragma unroll
      for (int r = 0; r < 4; ++r)
        out[(size_t)(nb + q * 4 + r) * 256] = __float2half(acc[r]);
    }
    __syncthreads();
  }
}

// ---------------- GATv2 fused: folded-leaky score + base-2 softmax + agg + LN --
// 8 rows in flight + next-batch index prefetch (software pipeline: the scalar
// csr_src loads of batch k+1 overlap batch k's row loads and compute).
__global__ __launch_bounds__(256) void k_gat_fused(
    const int* __restrict__ row_ptr, const int* __restrict__ csr_src,
    const __half* __restrict__ xl, const __half* __restrict__ xr,
    const float* __restrict__ att, const float* __restrict__ gat_b,
    const float* __restrict__ g, const float* __restrict__ bb,
    const __half* __restrict__ h_init16, __half* __restrict__ h2_16) {
  int n = wave_node();
  int lane = threadIdx.x & 63;
  const float LOG2E = 1.44269504088896f;
  float4 atv = *reinterpret_cast<const float4*>(att + lane * 4);
  // leaky folded: score = (0.6 att L)·t + (0.4 att L)·|t|, exponent base-2
  __half2 p0 = __floats2half2_rn(atv.x * (0.6f * LOG2E), atv.y * (0.6f * LOG2E));
  __half2 p1 = __floats2half2_rn(atv.z * (0.6f * LOG2E), atv.w * (0.6f * LOG2E));
  __half2 q0h = __floats2half2_rn(atv.x * (0.4f * LOG2E), atv.y * (0.4f * LOG2E));
  __half2 q1h = __floats2half2_rn(atv.z * (0.4f * LOG2E), atv.w * (0.4f * LOG2E));
  half4v R = *reinterpret_cast<const half4v*>(xr + (size_t)n * 256 + lane * 4);
  half4v S = *reinterpret_cast<const half4v*>(xl + (size_t)n * 256 + lane * 4);

  float q = reduce16(edge_score(S, R, p0, p1, q0h, q1h));
  float w = fexp2(q);
  float den = w;
  float ax = w * (float)S[0], ay = w * (float)S[1];
  float az = w * (float)S[2], aw = w * (float)S[3];

  int beg = row_ptr[n], end = row_ptr[n + 1];
  int i = beg;
  if (i + 8 <= end) {
    // indices of the first batch
    int s0 = __builtin_amdgcn_readfirstlane(csr_src[i]);
    int s1 = __builtin_amdgcn_readfirstlane(csr_src[i + 1]);
    int s2 = __builtin_amdgcn_readfirstlane(csr_src[i + 2]);
    int s3 = __builtin_amdgcn_readfirstlane(csr_src[i + 3]);
    int s4 = __builtin_amdgcn_readfirstlane(csr_src[i + 4]);
    int s5 = __builtin_amdgcn_readfirstlane(csr_src[i + 5]);
    int s6 = __builtin_amdgcn_readfirstlane(csr_src[i + 6]);
    int s7 = __builtin_amdgcn_readfirstlane(csr_src[i + 7]);
    for (;;) {
      // issue the 8 row loads for the current batch
      half4v A0 = *reinterpret_cast<const half4v*>(xl + (size_t)s0 * 256 + lane * 4);
      half4v A1 = *reinterpret_cast<const half4v*>(xl + (size_t)s1 * 256 + lane * 4);
      half4v A2 = *reinterpret_cast<const half4v*>(xl + (size_t)s2 * 256 + lane * 4);
      half4v A3 = *reinterpret_cast<const half4v*>(xl + (size_t)s3 * 256 + lane * 4);
      half4v A4 = *reinterpret_cast<const half4v*>(xl + (size_t)s4 * 256 + lane * 4);
      half4v A5 = *reinterpret_cast<const half4v*>(xl + (size_t)s5 * 256 + lane * 4);
      half4v A6 = *reinterpret_cast<const half4v*>(xl + (size_t)s6 * 256 + lane * 4);
      half4v A7 = *reinterpret_cast<const half4v*>(xl + (size_t)s7 * 256 + lane * 4);
      // prefetch next batch's indices (clamped to a safe dummy base so the
      // loads are unconditional straight-line code)
      int j = i + 8;
      int nb = (j + 8 <= end) ? j : beg;
      int t0 = __builtin_amdgcn_readfirstlane(csr_src[nb]);
      int t1 = __builtin_amdgcn_readfirstlane(csr_src[nb + 1]);
      int t2 = __builtin_amdgcn_readfirstlane(csr_src[nb + 2]);
      int t3 = __builtin_amdgcn_readfirstlane(csr_src[nb + 3]);
      int t4 = __builtin_amdgcn_readfirstlane(csr_src[nb + 4]);
      int t5 = __builtin_amdgcn_readfirstlane(csr_src[nb + 5]);
      int t6 = __builtin_amdgcn_readfirstlane(csr_src[nb + 6]);
      int t7 = __builtin_amdgcn_readfirstlane(csr_src[nb + 7]);
      // compute on the current batch
      f32x2 qa, qb, qc, qd;
      qa[0] = edge_score(A0, R, p0, p1, q0h, q1h);
      qa[1] = edge_score(A1, R, p0, p1, q0h, q1h);
      qb[0] = edge_score(A2, R, p0, p1, q0h, q1h);
      qb[1] = edge_score(A3, R, p0, p1, q0h, q1h);
      qc[0] = edge_score(A4, R, p0, p1, q0h, q1h);
      qc[1] = edge_score(A5, R, p0, p1, q0h, q1h);
      qd[0] = edge_score(A6, R, p0, p1, q0h, q1h);
      qd[1] = edge_score(A7, R, p0, p1, q0h, q1h);
#pragma unroll
      for (int o = 1; o <= 8; o <<= 1) {
        f32x2 ta, tb, tc, td;
        ta[0] = __shfl_xor(qa[0], o); ta[1] = __shfl_xor(qa[1], o);
        tb[0] = __shfl_xor(qb[0], o); tb[1] = __shfl_xor(qb[1], o);
        tc[0] = __shfl_xor(qc[0], o); tc[1] = __shfl_xor(qc[1], o);
        td[0] = __shfl_xor(qd[0], o); td[1] = __shfl_xor(qd[1], o);
        qa = qa + ta; qb = qb + tb; qc = qc + tc; qd = qd + td;
      }
      float w0 = fexp2(qa[0]), w1 = fexp2(qa[1]);
      float w2 = fexp2(qb[0]), w3 = fexp2(qb[1]);
      float w4 = fexp2(qc[0]), w5 = fexp2(qc[1]);
      float w6 = fexp2(qd[0]), w7 = fexp2(qd[1]);
      den += ((w0 + w1) + (w2 + w3)) + ((w4 + w5) + (w6 + w7));
      ax = fmaf(w0, (float)A0[0], ax); ax = fmaf(w1, (float)A1[0], ax);
      ax = fmaf(w2, (float)A2[0], ax); ax = fmaf(w3, (float)A3[0], ax);
      ax = fmaf(w4, (float)A4[0], ax); ax = fmaf(w5, (float)A5[0], ax);
      ax = fmaf(w6, (float)A6[0], ax); ax = fmaf(w7, (float)A7[0], ax);
      ay = fmaf(w0, (float)A0[1], ay); ay = fmaf(w1, (float)A1[1], ay);
      ay = fmaf(w2, (float)A2[1], ay); ay = fmaf(w3, (float)A3[1], ay);
      ay = fmaf(w4, (float)A4[1], ay); ay = fmaf(w5, (float)A5[1], ay);
      ay = fmaf(w6, (float)A6[1], ay); ay = fmaf(w7, (float)A7[1], ay);
      az = fmaf(w0, (float)A0[2], az); az = fmaf(w1, (float)A1[2], az);
      az = fmaf(w2, (float)A2[2], az); az = fmaf(w3, (float)A3[2], az);
      az = fmaf(w4, (float)A4[2], az); az = fmaf(w5, (float)A5[2], az);
      az = fmaf(w6, (float)A6[2], az); az = fmaf(w7, (float)A7[2], az);
      aw = fmaf(w0, (float)A0[3], aw); aw = fmaf(w1, (float)A1[3], aw);
      aw = fmaf(w2, (float)A2[3], aw); aw = fmaf(w3, (float)A3[3], aw);
      aw = fmaf(w4, (float)A4[3], aw); aw = fmaf(w5, (float)A5[3], aw);
      aw = fmaf(w6, (float)A6[3], aw); aw = fmaf(w7, (float)A7[3], aw);
      i = j;
      if (j + 8 > end) break;
      s0 = t0; s1 = t1; s2 = t2; s3 = t3;
      s4 = t4; s5 = t5; s6 = t6; s7 = t7;
    }
  }
  for (; i + 4 <= end; i += 4) {
    int s0 = __builtin_amdgcn_readfirstlane(csr_src[i]);
    int s1 = __builtin_amdgcn_readfirstlane(csr_src[i + 1]);
    int s2 = __builtin_amdgcn_readfirstlane(csr_src[i + 2]);
    int s3 = __builtin_amdgcn_readfirstlane(csr_src[i + 3]);
    half4v A0 = *reinterpret_cast<const half4v*>(xl + (size_t)s0 * 256 + lane * 4);
    half4v A1 = *reinterpret_cast<const half4v*>(xl + (size_t)s1 * 256 + lane * 4);
    half4v A2 = *reinterpret_cast<const half4v*>(xl + (size_t)s2 * 256 + lane * 4);
    half4v A3 = *reinterpret_cast<const half4v*>(xl + (size_t)s3 * 256 + lane * 4);
    f32x2 qa, qb;
    qa[0] = edge_score(A0, R, p0, p1, q0h, q1h);
    qa[1] = edge_score(A1, R, p0, p1, q0h, q1h);
    qb[0] = edge_score(A2, R, p0, p1, q0h, q1h);
    qb[1] = edge_score(A3, R, p0, p1, q0h, q1h);
#pragma unroll
    for (int o = 1; o <= 8; o <<= 1) {
      f32x2 ta, tb;
      ta[0] = __shfl_xor(qa[0], o); ta[1] = __shfl_xor(qa[1], o);
      tb[0] = __shfl_xor(qb[0], o); tb[1] = __shfl_xor(qb[1], o);
      qa = qa + ta; qb = qb + tb;
    }
    float w0 = fexp2(qa[0]), w1 = fexp2(qa[1]);
    float w2 = fexp2(qb[0]), w3 = fexp2(qb[1]);
    den += (w0 + w1) + (w2 + w3);
    ax = fmaf(w0, (float)A0[0], ax); ax = fmaf(w1, (float)A1[0], ax);
    ax = fmaf(w2, (float)A2[0], ax); ax = fmaf(w3, (float)A3[0], ax);
    ay = fmaf(w0, (float)A0[1], ay); ay = fmaf(w1, (float)A1[1], ay);
    ay = fmaf(w2, (float)A2[1], ay); ay = fmaf(w3, (float)A3[1], ay);
    az = fmaf(w0, (float)A0[2], az); az = fmaf(w1, (float)A1[2], az);
    az = fmaf(w2, (float)A2[2], az); az = fmaf(w3, (float)A3[2], az);
    aw = fmaf(w0, (float)A0[3], aw); aw = fmaf(w1, (float)A1[3], aw);
    aw = fmaf(w2, (float)A2[3], aw); aw = fmaf(w3, (float)A3[3], aw);
  }
  for (; i < end; ++i) {
    int s0 = __builtin_amdgcn_readfirstlane(csr_src[i]);
    half4v A0 = *reinterpret_cast<const half4v*>(xl + (size_t)s0 * 256 + lane * 4);
    q = reduce16(edge_score(A0, R, p0, p1, q0h, q1h));
    w = fexp2(q);
    den += w;
    ax = fmaf(w, (float)A0[0], ax); ay = fmaf(w, (float)A0[1], ay);
    az = fmaf(w, (float)A0[2], az); aw = fmaf(w, (float)A0[3], aw);
  }
  float inv = 1.f / den;
  ax *= inv; ay *= inv; az *= inv; aw *= inv;
  // mean over heads: lanes l, l^16, l^32, l^48 hold same feature of different heads
  ax += __shfl_xor(ax, 16); ay += __shfl_xor(ay, 16);
  az += __shfl_xor(az, 16); aw += __shfl_xor(aw, 16);
  ax += __shfl_xor(ax, 32); ay += __shfl_xor(ay, 32);
  az += __shfl_xor(az, 32); aw += __shfl_xor(aw, 32);
  // redistribute: feature `lane` = component (lane&3) of lane (lane>>2)
  int srcl = lane >> 2;
  float t0 = __shfl(ax, srcl), t1 = __shfl(ay, srcl);
  float t2 = __shfl(az, srcl), t3 = __shfl(aw, srcl);
  int r = lane & 3;
  float mean = (r == 0) ? t0 : (r == 1) ? t1 : (r == 2) ? t2 : t3;
  float val = mean * 0.25f + gat_b[lane];
  float mu = wsum(val) * (1.f / HID);
  float dv = val - mu;
  float var = wsum(dv * dv) * (1.f / HID);
  float h = dv * rsqrtf(var + 1e-5f) * g[lane] + bb[lane];
  h = h > 0.f ? h : 0.f;
  float outv = h + __half2float(h_init16[(size_t)n * HID + lane]);
  h2_16[(size_t)n * HID + lane] = __float2half(outv);
}

// ---------------- SAGE stage 1: pull mean-gather (fp16 out, n in SGPR, 8x MLP) --
__global__ __launch_bounds__(256) void k_sage_gather(
    const int* __restrict__ row_ptr, const int* __restrict__ csr_src,
    const __half* __restrict__ h2_16, __half* __restrict__ nmean16) {
  int n = wave_node();
  int lane = threadIdx.x & 63;
  int beg = row_ptr[n], end = row_ptr[n + 1];
  float sum = 0.f, sum2 = 0.f;
  int i = beg;
  for (; i + 8 <= end; i += 8) {
    int s0 = __builtin_amdgcn_readfirstlane(csr_src[i]);
    int s1 = __builtin_amdgcn_readfirstlane(csr_src[i + 1]);
    int s2 = __builtin_amdgcn_readfirstlane(csr_src[i + 2]);
    int s3 = __builtin_amdgcn_readfirstlane(csr_src[i + 3]);
    int s4 = __builtin_amdgcn_readfirstlane(csr_src[i + 4]);
    int s5 = __builtin_amdgcn_readfirstlane(csr_src[i + 5]);
    int s6 = __builtin_amdgcn_readfirstlane(csr_src[i + 6]);
    int s7 = __builtin_amdgcn_readfirstlane(csr_src[i + 7]);
    float v0 = __half2float(h2_16[(size_t)s0 * HID + lane]);
    float v1 = __half2float(h2_16[(size_t)s1 * HID + lane]);
    float v2 = __half2float(h2_16[(size_t)s2 * HID + lane]);
    float v3 = __half2float(h2_16[(size_t)s3 * HID + lane]);
    float v4 = __half2float(h2_16[(size_t)s4 * HID + lane]);
    float v5 = __half2float(h2_16[(size_t)s5 * HID + lane]);
    float v6 = __half2float(h2_16[(size_t)s6 * HID + lane]);
    float v7 = __half2float(h2_16[(size_t)s7 * HID + lane]);
    sum  += (v0 + v1) + (v2 + v3);
    sum2 += (v4 + v5) + (v6 + v7);
  }
  for (; i + 4 <= end; i += 4) {
    int s0 = __builtin_amdgcn_readfirstlane(csr_src[i]);
    int s1 = __builtin_amdgcn_readfirstlane(csr_src[i + 1]);
    int s2 = __builtin_amdgcn_readfirstlane(csr_src[i + 2]);
    int s3 = __builtin_amdgcn_readfirstlane(csr_src[i + 3]);
    float v0 = __half2float(h2_16[(size_t)s0 * HID + lane]);
    float v1 = __half2float(h2_16[(size_t)s1 * HID + lane]);
    float v2 = __half2float(h2_16[(size_t)s2 * HID + lane]);
    float v3 = __half2float(h2_16[(size_t)s3 * HID + lane]);
    sum += (v0 + v1) + (v2 + v3);
  }
  for (; i < end; ++i) {
    int s = __builtin_amdgcn_readfirstlane(csr_src[i]);
    sum += __half2float(h2_16[(size_t)s * HID + lane]);
  }
  nmean16[(size_t)n * HID + lane] =
      __float2half((sum + sum2) / fmaxf((float)(end - beg), 1.f));
}

// ---------------- SAGE stage 2 + heads (fused): h3 never materialized ----------
__global__ __launch_bounds__(64) void k_sage_gemm_ln_heads(
    const __half* __restrict__ nmean16, const __half* __restrict__ h2_16,
    const __half* __restrict__ h_init16,
    const float* __restrict__ Wl, const float* __restrict__ Wr,
    const float* __restrict__ sage_bl, const float* __restrict__ g,
    const float* __restrict__ bb, const int* __restrict__ mask,
    const float* __restrict__ mort_W, const float* __restrict__ mort_b,
    const float* __restrict__ hours_W, const float* __restrict__ hours_b,
    const float* __restrict__ disc_W, const float* __restrict__ disc_b,
    float* __restrict__ out) {
  __shared__ float nt[8][HID];
  __shared__ float ht[8][HID];
  int t = threadIdx.x;
  int n0 = blockIdx.x * 8;
  {
    const __half* np = nmean16 + (size_t)n0 * HID + t * 8;
    const __half* hp = h2_16 + (size_t)n0 * HID + t * 8;
    Half4 n0v = *reinterpret_cast<const Half4*>(np);
    Half4 n1v = *reinterpret_cast<const Half4*>(np + 4);
    Half4 p0 = *reinterpret_cast<const Half4*>(hp);
    Half4 p1 = *reinterpret_cast<const Half4*>(hp + 4);
    float* dn = &nt[0][0] + t * 8;
    float* dh = &ht[0][0] + t * 8;
    float2 f;
    f = __half22float2(n0v.a); dn[0] = f.x; dn[1] = f.y;
    f = __half22float2(n0v.b); dn[2] = f.x; dn[3] = f.y;
    f = __half22float2(n1v.a); dn[4] = f.x; dn[5] = f.y;
    f = __half22float2(n1v.b); dn[6] = f.x; dn[7] = f.y;
    f = __half22float2(p0.a);  dh[0] = f.x; dh[1] = f.y;
    f = __half22float2(p0.b);  dh[2] = f.x; dh[3] = f.y;
    f = __half22float2(p1.a);  dh[4] = f.x; dh[5] = f.y;
    f = __half22float2(p1.b);  dh[6] = f.x; dh[7] = f.y;
  }
  __syncthreads();
  int f = t;
  float acc[8] = {0.f,0.f,0.f,0.f,0.f,0.f,0.f,0.f};
  for (int k = 0; k < HID; k += 4) {
    float wl0 = Wl[(k + 0) * HID + f], wr0 = Wr[(k + 0) * HID + f];
    float wl1 = Wl[(k + 1) * HID + f], wr1 = Wr[(k + 1) * HID + f];
    float wl2 = Wl[(k + 2) * HID + f], wr2 = Wr[(k + 2) * HID + f];
    float wl3 = Wl[(k + 3) * HID + f], wr3 = Wr[(k + 3) * HID + f];
#pragma unroll
    for (int j = 0; j < 8; ++j) {
      float4 nv = *reinterpret_cast<const float4*>(&nt[j][k]);
      float4 hv = *reinterpret_cast<const float4*>(&ht[j][k]);
      acc[j] += nv.x * wl0 + nv.y * wl1 + nv.z * wl2 + nv.w * wl3
              + hv.x * wr0 + hv.y * wr1 + hv.z * wr2 + hv.w * wr3;
    }
  }
  float blv = sage_bl[f], gv = g[f], bbv = bb[f];
  float mw0 = mort_W[f], mw1 = mort_W[64 + f], mw2 = mort_W[128 + f];
  float hw0 = hours_W[f], hw1 = hours_W[64 + f], hw2 = hours_W[128 + f];
  float dwv[12];
#pragma unroll
  for (int rr = 0; rr < 3; ++rr)
#pragma unroll
    for (int c = 0; c < 4; ++c)
      dwv[rr * 4 + c] = disc_W[(rr * 64 + f) * 4 + c];
#pragma unroll
  for (int j = 0; j < 8; ++j) {
    float v = acc[j] + blv;
    float mu = wsum(v) * (1.f / HID);
    float dv = v - mu;
    float var = wsum(dv * dv) * (1.f / HID);
    float h = dv * rsqrtf(var + 1e-5f) * gv + bbv;
    h = h > 0.f ? h : 0.f;
    int n = n0 + j;
    float m = (mask[n] != 0) ? 1.f : 0.f;
    float v2 = (h + ht[j][f]) * m;                        // h3
    float v1 = ht[j][f] * m;                              // h2
    float v0 = __half2float(h_init16[(size_t)n * HID + f]) * m;
    float pm = v0 * mw0 + v1 * mw1 + v2 * mw2;
    float ph = v0 * hw0 + v1 * hw1 + v2 * hw2;
    float d0 = v0 * dwv[0] + v1 * dwv[4] + v2 * dwv[8];
    float d1 = v0 * dwv[1] + v1 * dwv[5] + v2 * dwv[9];
    float d2 = v0 * dwv[2] + v1 * dwv[6] + v2 * dwv[10];
    float d3 = v0 * dwv[3] + v1 * dwv[7] + v2 * dwv[11];
    pm = wsum(pm); ph = wsum(ph);
    d0 = wsum(d0); d1 = wsum(d1); d2 = wsum(d2); d3 = wsum(d3);
    if (f == 0) {
      out[n] = pm + mort_b[0];
      out[N_NODES + n] = ph + hours_b[0];
      float* dd = out + 2 * N_NODES + (size_t)n * 4;
      dd[0] = d0 + disc_b[0];
      dd[1] = d1 + disc_b[1];
      dd[2] = d2 + disc_b[2];
      dd[3] = d3 + disc_b[3];
    }
  }
}

extern "C" void kernel_launch(void* const* d_in, const int* in_sizes, int n_in,
                              void* d_out, int out_size, void* d_ws, size_t ws_size,
                              hipStream_t stream) {
  const float* x       = (const float*)d_in[0];
  const int*   ei      = (const int*)d_in[1];
  const float* ew      = (const float*)d_in[2];
  const int*   mask    = (const int*)d_in[3];
  const float* gcn_W   = (const float*)d_in[4];
  const float* gcn_b   = (const float*)d_in[5];
  const float* proj_W  = (const float*)d_in[6];
  const float* proj_b  = (const float*)d_in[7];
  const float* ln1_g   = (const float*)d_in[8];
  const float* ln1_b   = (const float*)d_in[9];
  const float* gat_Wl  = (const float*)d_in[10];
  const float* gat_Wr  = (const float*)d_in[11];
  const float* gat_att = (const float*)d_in[12];
  const float* gat_b   = (const float*)d_in[13];
  const float* ln2_g   = (const float*)d_in[14];
  const float* ln2_b   = (const float*)d_in[15];
  const float* sage_Wl = (const float*)d_in[16];
  const float* sage_bl = (const float*)d_in[17];
  const float* sage_Wr = (const float*)d_in[18];
  const float* ln3_g   = (const float*)d_in[19];
  const float* ln3_b   = (const float*)d_in[20];
  // d_in[21..24]: edge-MLP params — output unused by the reference; skipped.
  const float* mort_W  = (const float*)d_in[25];
  const float* mort_b  = (const float*)d_in[26];
  const float* hours_W = (const float*)d_in[27];
  const float* hours_b = (const float*)d_in[28];
  const float* disc_W  = (const float*)d_in[29];
  const float* disc_b  = (const float*)d_in[30];

  const int* src = ei;
  const int* dst = ei + N_EDGES;
  float* out = (float*)d_out;

  // ---- workspace layout ----
  float* ws = (float*)d_ws;
  const size_t F = (size_t)N_NODES * HID;  // 6.4M floats
  __half* xp16  = (__half*)(ws + 2 * F);           // N*64 halfs
  __half* xl    = (__half*)(ws + 3 * F);           // N*256 halfs
  __half* xw16  = xl;                              // N*64 halfs, dead before xl written
  __half* nmean16 = (__half*)(ws + 3 * F);         // N*64 halfs, xl dead by SAGE
  __half* xr    = (__half*)(ws + 3 * F + (size_t)N_NODES * 128);
  __half* h2_16 = (__half*)(ws + 3 * F + (size_t)N_NODES * 256);
  __half* h_init16 = (__half*)(ws + 3 * F + (size_t)N_NODES * 288);
  float* tail   = ws + 3 * F + (size_t)N_NODES * 320;
  int*   csr_src = (int*)tail;           tail += N_EDGES;
  float* csr_w   = tail;                 tail += N_EDGES;
  int*   row_ptr = (int*)tail;           tail += N_NODES + 64;
  int*   cursor  = (int*)tail;           tail += N_NODES;
  int*   cnt     = (int*)tail;           tail += N_NODES;
  int*   partial = (int*)tail;           tail += N_NODES;
  int*   bsum    = (int*)tail;           tail += 128;
  float* dinv    = tail;

  const int GE = (N_EDGES + 255) / 256;
  const int GN = (N_NODES + 255) / 256;
  const int GB = N_NODES / (16 * GEMM_NT);  // 1250 blocks for MFMA GEMMs

  // --- CSR build (by dst) ---
  hipMemsetAsync(cnt, 0, N_NODES * sizeof(int), stream);
  k_hist<<<GE, 256, 0, stream>>>(dst, cnt);
  k_scan1<<<SCAN_BLK, 256, 0, stream>>>(cnt, partial, bsum);
  k_scan3<<<GN, 256, 0, stream>>>(partial, bsum, row_ptr, cursor);
  k_fill<<<GE, 256, 0, stream>>>(src, dst, ew, cursor, csr_src, csr_w);

  // --- GCN layer ---
  k_in_gemm_mfma<<<GB, 512, 0, stream>>>(x, gcn_W, proj_W, proj_b, xw16, xp16);
  k_deg<<<GN, 256, 0, stream>>>(row_ptr, csr_w, dinv);
  k_gcn_fused<<<N_NODES / 4, 256, 0, stream>>>(row_ptr, csr_src, csr_w, dinv, xw16,
                                               xp16, gcn_b, ln1_g, ln1_b, h_init16);

  // --- GATv2 layer ---
  k_gat_gemm_mfma<<<GB, 512, 0, stream>>>(h_init16, gat_Wl, gat_Wr, xl, xr);
  k_gat_fused<<<N_NODES / 4, 256, 0, stream>>>(row_ptr, csr_src, xl, xr, gat_att,
                                               gat_b, ln2_g, ln2_b, h_init16, h2_16);

  // --- SAGE layer + heads (fused) ---
  k_sage_gather<<<N_NODES / 4, 256, 0, stream>>>(row_ptr, csr_src, h2_16, nmean16);
  k_sage_gemm_ln_heads<<<N_NODES / 8, 64, 0, stream>>>(
      nmean16, h2_16, h_init16, sage_Wl, sage_Wr, sage_bl, ln3_g, ln3_b, mask,
      mort_W, mort_b, hours_W, hours_b, disc_W, disc_b, out);
}

// Round 7
// 555.560 us; speedup vs baseline: 1.0418x; 1.0418x over previous
//
#include <hip/hip_runtime.h>
#include <hip/hip_fp16.h>
#include <math.h>

#define N_NODES 100000
#define N_EDGES 1000000
#define F_IN    128
#define HID     64
#define HEADS   4
#define NCLS    4
#define SCAN_BLK 98   // ceil(N_NODES / 1024)
#define GEMM_NT 5     // node-tiles per block in MFMA GEMMs (80 nodes/block)

typedef _Float16 half8 __attribute__((ext_vector_type(8)));
typedef _Float16 half4v __attribute__((ext_vector_type(4)));
typedef _Float16 fp16x2 __attribute__((ext_vector_type(2)));
typedef float f32x4 __attribute__((ext_vector_type(4)));
typedef float f32x2 __attribute__((ext_vector_type(2)));

// ---------------- helpers ----------------
__device__ __forceinline__ float wsum(float v) {
#pragma unroll
  for (int o = 32; o > 0; o >>= 1) v += __shfl_xor(v, o, 64);
  return v;
}
struct Half4 { __half2 a, b; };
__device__ __forceinline__ __half2 absh2(__half2 v) {
  unsigned u; __builtin_memcpy(&u, &v, 4);
  u &= 0x7FFF7FFFu;
  __half2 r; __builtin_memcpy(&r, &u, 4);
  return r;
}
__device__ __forceinline__ float fdot2f(__half2 a, __half2 b, float c) {
#if defined(__has_builtin) && __has_builtin(__builtin_amdgcn_fdot2)
  fp16x2 av, bv;
  __builtin_memcpy(&av, &a, 4); __builtin_memcpy(&bv, &b, 4);
  return __builtin_amdgcn_fdot2(av, bv, c, false);
#else
  float2 af = __half22float2(a), bf = __half22float2(b);
  return c + af.x * bf.x + af.y * bf.y;
#endif
}
__device__ __forceinline__ float fexp2(float x) {
#if defined(__has_builtin) && __has_builtin(__builtin_amdgcn_exp2f)
  return __builtin_amdgcn_exp2f(x);
#else
  return exp2f(x);
#endif
}
__device__ __forceinline__ __half2 h2of4(half4v v, int p) {
  fp16x2 t; t[0] = v[2 * p]; t[1] = v[2 * p + 1];
  __half2 r; __builtin_memcpy(&r, &t, 4);
  return r;
}
// score partial over this lane's 4 feats with leaky folded into att:
// score = (0.6*att*log2e)·t + (0.4*att*log2e)·|t|,  t = A + R  (base-2 exponent)
__device__ __forceinline__ float edge_score(half4v A, half4v R,
                                            __half2 p0, __half2 p1,
                                            __half2 q0, __half2 q1) {
  __half2 t0 = __hadd2(h2of4(A, 0), h2of4(R, 0));
  __half2 t1 = __hadd2(h2of4(A, 1), h2of4(R, 1));
  float s = fdot2f(t0, p0, 0.f);
  s = fdot2f(t1, p1, s);
  s = fdot2f(absh2(t0), q0, s);
  s = fdot2f(absh2(t1), q1, s);
  return s;
}
__device__ __forceinline__ float reduce16(float q) {
  q += __shfl_xor(q, 1); q += __shfl_xor(q, 2);
  q += __shfl_xor(q, 4); q += __shfl_xor(q, 8);
  return q;
}
// wave-uniform node id -> SGPR (row_ptr/csr reads become scalar loads)
__device__ __forceinline__ int wave_node() {
  return __builtin_amdgcn_readfirstlane(blockIdx.x * 4 + (threadIdx.x >> 6));
}

// ---------------- CSR build (by dst) ----------------
__global__ void k_hist(const int* __restrict__ dst, int* __restrict__ cnt) {
  int e = blockIdx.x * 256 + threadIdx.x;
  if (e < N_EDGES) atomicAdd(&cnt[dst[e]], 1);
}
__global__ __launch_bounds__(256) void k_scan1(const int* __restrict__ cnt,
                                               int* __restrict__ partial,
                                               int* __restrict__ bsum) {
  __shared__ int lds[256];
  int t = threadIdx.x;
  int base = blockIdx.x * 1024 + t * 4;
  int v0 = (base + 0 < N_NODES) ? cnt[base + 0] : 0;
  int v1 = (base + 1 < N_NODES) ? cnt[base + 1] : 0;
  int v2 = (base + 2 < N_NODES) ? cnt[base + 2] : 0;
  int v3 = (base + 3 < N_NODES) ? cnt[base + 3] : 0;
  int s = v0 + v1 + v2 + v3;
  lds[t] = s;
  __syncthreads();
  for (int o = 1; o < 256; o <<= 1) {
    int x = (t >= o) ? lds[t - o] : 0;
    __syncthreads();
    lds[t] += x;
    __syncthreads();
  }
  int excl = lds[t] - s;
  if (base + 0 < N_NODES) partial[base + 0] = excl;
  if (base + 1 < N_NODES) partial[base + 1] = excl + v0;
  if (base + 2 < N_NODES) partial[base + 2] = excl + v0 + v1;
  if (base + 3 < N_NODES) partial[base + 3] = excl + v0 + v1 + v2;
  if (t == 255) bsum[blockIdx.x] = lds[255];
}
// scan of bsum folded in: every block redundantly scans the 98 block-sums.
__global__ __launch_bounds__(256) void k_scan3(const int* __restrict__ partial,
                                               const int* __restrict__ bsum,
                                               int* __restrict__ row_ptr,
                                               int* __restrict__ cursor) {
  __shared__ int ex[128];
  int t = threadIdx.x;
  int orig = 0;
  if (t < 128) {
    orig = (t < SCAN_BLK) ? bsum[t] : 0;
    ex[t] = orig;
  }
  __syncthreads();
  for (int o = 1; o < 128; o <<= 1) {
    int x = (t < 128 && t >= o) ? ex[t - o] : 0;
    __syncthreads();
    if (t < 128) ex[t] += x;
    __syncthreads();
  }
  if (t < 128) ex[t] -= orig;  // exclusive
  __syncthreads();
  int i = blockIdx.x * 256 + t;
  if (i < N_NODES) {
    int v = partial[i] + ex[i >> 10];
    row_ptr[i] = v;
    cursor[i] = v;
  }
  if (i == 0) row_ptr[N_NODES] = N_EDGES;
}
__global__ void k_fill(const int* __restrict__ src, const int* __restrict__ dst,
                       const float* __restrict__ ew, int* __restrict__ cursor,
                       int* __restrict__ csr_src, float* __restrict__ csr_w) {
  int e = blockIdx.x * 256 + threadIdx.x;
  if (e >= N_EDGES) return;
  int d = dst[e];
  int p = atomicAdd(&cursor[d], 1);
  csr_src[p] = src[e];
  csr_w[p] = ew[e];
}

// ---------------- MFMA GEMM 1: [xw16|xp16] = x @ [gcn_W|proj_W]  (K=128, N=128) --
__global__ __launch_bounds__(512) void k_in_gemm_mfma(
    const float* __restrict__ x, const float* __restrict__ gcn_W,
    const float* __restrict__ proj_W, const float* __restrict__ proj_b,
    __half* __restrict__ xw16, __half* __restrict__ xp16) {
  __shared__ __half at[16 * 136];
  int t = threadIdx.x;
  int w = t >> 6, lane = t & 63;
  int m = lane & 15, q = lane >> 4;
  int ncol = w * 16 + m;                 // 0..127
  const float* W = (ncol < 64) ? gcn_W : proj_W;
  int nc = (ncol < 64) ? ncol : ncol - 64;
  half8 bf[4];
#pragma unroll
  for (int ch = 0; ch < 4; ++ch) {
    int kb = ch * 32 + q * 8;
#pragma unroll
    for (int j = 0; j < 8; ++j)
      bf[ch][j] = (_Float16)W[(kb + j) * 64 + nc];
  }
  float pb = (ncol >= 64) ? proj_b[nc] : 0.f;
  int nb0 = blockIdx.x * (16 * GEMM_NT);
  for (int nt = 0; nt < GEMM_NT; ++nt) {
    int nb = nb0 + nt * 16;
    {
      int row = t >> 5, col = (t & 31) * 4;
      float4 v = *reinterpret_cast<const float4*>(x + (size_t)(nb + row) * F_IN + col);
      __half2* d = reinterpret_cast<__half2*>(&at[row * 136 + col]);
      d[0] = __floats2half2_rn(v.x, v.y);
      d[1] = __floats2half2_rn(v.z, v.w);
    }
    __syncthreads();
    f32x4 acc = {0.f, 0.f, 0.f, 0.f};
#pragma unroll
    for (int ch = 0; ch < 4; ++ch) {
      half8 af = *reinterpret_cast<const half8*>(&at[m * 136 + ch * 32 + q * 8]);
      acc = __builtin_amdgcn_mfma_f32_16x16x32_f16(af, bf[ch], acc, 0, 0, 0);
    }
    if (ncol < 64) {
#pragma unroll
      for (int r = 0; r < 4; ++r)
        xw16[(size_t)(nb + q * 4 + r) * HID + nc] = __float2half(acc[r]);
    } else {
#pragma unroll
      for (int r = 0; r < 4; ++r)
        xp16[(size_t)(nb + q * 4 + r) * HID + nc] = __float2half(acc[r] + pb);
    }
    __syncthreads();
  }
}

// ---------------- GCN: deg/dinv from CSR (no atomics) ----------------
__global__ void k_deg(const int* __restrict__ row_ptr, const float* __restrict__ csr_w,
                      float* __restrict__ dinv) {
  int n = blockIdx.x * 256 + threadIdx.x;
  if (n >= N_NODES) return;
  float deg = 1.0f;  // self-loop weight
  int end = row_ptr[n + 1];
  for (int i = row_ptr[n]; i < end; ++i) deg += csr_w[i];
  dinv[n] = rsqrtf(deg);  // deg >= 1 always
}

// pull-gather + LN + relu + residual, one wave per node (n in SGPR), 8x MLP
__global__ __launch_bounds__(256) void k_gcn_fused(
    const int* __restrict__ row_ptr, const int* __restrict__ csr_src,
    const float* __restrict__ csr_w, const float* __restrict__ dinv,
    const __half* __restrict__ xw16, const __half* __restrict__ xp16,
    const float* __restrict__ gcn_b, const float* __restrict__ g,
    const float* __restrict__ bb, __half* __restrict__ h_init16) {
  int n = wave_node();
  int lane = threadIdx.x & 63;
  float di = dinv[n];
  float acc = di * di * __half2float(xw16[(size_t)n * HID + lane]);  // self loop
  float acc2 = 0.f;
  int beg = row_ptr[n], end = row_ptr[n + 1];
  int i = beg;
  for (; i + 8 <= end; i += 8) {
    int s0 = __builtin_amdgcn_readfirstlane(csr_src[i]);
    int s1 = __builtin_amdgcn_readfirstlane(csr_src[i + 1]);
    int s2 = __builtin_amdgcn_readfirstlane(csr_src[i + 2]);
    int s3 = __builtin_amdgcn_readfirstlane(csr_src[i + 3]);
    int s4 = __builtin_amdgcn_readfirstlane(csr_src[i + 4]);
    int s5 = __builtin_amdgcn_readfirstlane(csr_src[i + 5]);
    int s6 = __builtin_amdgcn_readfirstlane(csr_src[i + 6]);
    int s7 = __builtin_amdgcn_readfirstlane(csr_src[i + 7]);
    float nrm0 = dinv[s0] * csr_w[i] * di;
    float nrm1 = dinv[s1] * csr_w[i + 1] * di;
    float nrm2 = dinv[s2] * csr_w[i + 2] * di;
    float nrm3 = dinv[s3] * csr_w[i + 3] * di;
    float nrm4 = dinv[s4] * csr_w[i + 4] * di;
    float nrm5 = dinv[s5] * csr_w[i + 5] * di;
    float nrm6 = dinv[s6] * csr_w[i + 6] * di;
    float nrm7 = dinv[s7] * csr_w[i + 7] * di;
    float v0 = __half2float(xw16[(size_t)s0 * HID + lane]);
    float v1 = __half2float(xw16[(size_t)s1 * HID + lane]);
    float v2 = __half2float(xw16[(size_t)s2 * HID + lane]);
    float v3 = __half2float(xw16[(size_t)s3 * HID + lane]);
    float v4 = __half2float(xw16[(size_t)s4 * HID + lane]);
    float v5 = __half2float(xw16[(size_t)s5 * HID + lane]);
    float v6 = __half2float(xw16[(size_t)s6 * HID + lane]);
    float v7 = __half2float(xw16[(size_t)s7 * HID + lane]);
    acc  += nrm0 * v0 + nrm1 * v1 + nrm2 * v2 + nrm3 * v3;
    acc2 += nrm4 * v4 + nrm5 * v5 + nrm6 * v6 + nrm7 * v7;
  }
  for (; i + 4 <= end; i += 4) {
    int s0 = __builtin_amdgcn_readfirstlane(csr_src[i]);
    int s1 = __builtin_amdgcn_readfirstlane(csr_src[i + 1]);
    int s2 = __builtin_amdgcn_readfirstlane(csr_src[i + 2]);
    int s3 = __builtin_amdgcn_readfirstlane(csr_src[i + 3]);
    float nrm0 = dinv[s0] * csr_w[i] * di;
    float nrm1 = dinv[s1] * csr_w[i + 1] * di;
    float nrm2 = dinv[s2] * csr_w[i + 2] * di;
    float nrm3 = dinv[s3] * csr_w[i + 3] * di;
    float v0 = __half2float(xw16[(size_t)s0 * HID + lane]);
    float v1 = __half2float(xw16[(size_t)s1 * HID + lane]);
    float v2 = __half2float(xw16[(size_t)s2 * HID + lane]);
    float v3 = __half2float(xw16[(size_t)s3 * HID + lane]);
    acc += nrm0 * v0 + nrm1 * v1 + nrm2 * v2 + nrm3 * v3;
  }
  for (; i < end; ++i) {
    int s = __builtin_amdgcn_readfirstlane(csr_src[i]);
    float nrm = dinv[s] * csr_w[i] * di;
    acc += nrm * __half2float(xw16[(size_t)s * HID + lane]);
  }
  float v = acc + acc2 + gcn_b[lane];
  float mu = wsum(v) * (1.f / HID);
  float dv = v - mu;
  float var = wsum(dv * dv) * (1.f / HID);
  float h = dv * rsqrtf(var + 1e-5f) * g[lane] + bb[lane];
  h = h > 0.f ? h : 0.f;
  h_init16[(size_t)n * HID + lane] =
      __float2half(h + __half2float(xp16[(size_t)n * HID + lane]));
}

// ---------------- MFMA GEMM 2: [xl|xr] = h16 @ [Wl|Wr]  (K=64, N=512) ----------
__global__ __launch_bounds__(512) void k_gat_gemm_mfma(
    const __half* __restrict__ h16, const float* __restrict__ Wl,
    const float* __restrict__ Wr, __half* __restrict__ xl, __half* __restrict__ xr) {
  __shared__ __half at[16 * 72];
  int t = threadIdx.x;
  int w = t >> 6, lane = t & 63;
  int m = lane & 15, q = lane >> 4;
  half8 bf[4][2];
#pragma unroll
  for (int tt = 0; tt < 4; ++tt) {
    int c = w * 16 + tt * 128 + m;          // 0..511
    const float* W = (c < 256) ? Wl : Wr;
    int nc = (c < 256) ? c : c - 256;
#pragma unroll
    for (int ch = 0; ch < 2; ++ch) {
      int kb = ch * 32 + q * 8;
#pragma unroll
      for (int j = 0; j < 8; ++j)
        bf[tt][ch][j] = (_Float16)W[(kb + j) * 256 + nc];
    }
  }
  int nb0 = blockIdx.x * (16 * GEMM_NT);
  for (int nt = 0; nt < GEMM_NT; ++nt) {
    int nb = nb0 + nt * 16;
    {
      int row = t >> 5, col = (t & 31) * 2;
      *reinterpret_cast<__half2*>(&at[row * 72 + col]) =
          *reinterpret_cast<const __half2*>(h16 + (size_t)(nb + row) * HID + col);
    }
    __syncthreads();
    half8 a0 = *reinterpret_cast<const half8*>(&at[m * 72 + q * 8]);
    half8 a1 = *reinterpret_cast<const half8*>(&at[m * 72 + 32 + q * 8]);
#pragma unroll
    for (int tt = 0; tt < 4; ++tt) {
      f32x4 acc = {0.f, 0.f, 0.f, 0.f};
      acc = __builtin_amdgcn_mfma_f32_16x16x32_f16(a0, bf[tt][0], acc, 0, 0, 0);
      acc = __builtin_amdgcn_mfma_f32_16x16x32_f16(a1, bf[tt][1], acc, 0, 0, 0);
      int c = w * 16 + tt * 128 + m;
      __half* out = (c < 256) ? (xl + c) : (xr + (c - 256));
#pragma unroll
      for (int r = 0; r < 4; ++r)
        out[(size_t)(nb + q * 4 + r) * 256] = __float2half(acc[r]);
    }
    __syncthreads();
  }
}

// ---------------- GATv2 fused: folded-leaky score + base-2 softmax + agg + LN --
// 8 edges in flight per iteration (MLP for the L2/L3-miss gather latency).
__global__ __launch_bounds__(256) void k_gat_fused(
    const int* __restrict__ row_ptr, const int* __restrict__ csr_src,
    const __half* __restrict__ xl, const __half* __restrict__ xr,
    const float* __restrict__ att, const float* __restrict__ gat_b,
    const float* __restrict__ g, const float* __restrict__ bb,
    const __half* __restrict__ h_init16, __half* __restrict__ h2_16) {
  int n = wave_node();
  int lane = threadIdx.x & 63;
  const float LOG2E = 1.44269504088896f;
  float4 atv = *reinterpret_cast<const float4*>(att + lane * 4);
  // leaky folded: score = (0.6 att L)·t + (0.4 att L)·|t|, exponent base-2
  __half2 p0 = __floats2half2_rn(atv.x * (0.6f * LOG2E), atv.y * (0.6f * LOG2E));
  __half2 p1 = __floats2half2_rn(atv.z * (0.6f * LOG2E), atv.w * (0.6f * LOG2E));
  __half2 q0h = __floats2half2_rn(atv.x * (0.4f * LOG2E), atv.y * (0.4f * LOG2E));
  __half2 q1h = __floats2half2_rn(atv.z * (0.4f * LOG2E), atv.w * (0.4f * LOG2E));
  half4v R = *reinterpret_cast<const half4v*>(xr + (size_t)n * 256 + lane * 4);
  half4v S = *reinterpret_cast<const half4v*>(xl + (size_t)n * 256 + lane * 4);

  float q = reduce16(edge_score(S, R, p0, p1, q0h, q1h));
  float w = fexp2(q);
  float den = w;
  float ax = w * (float)S[0], ay = w * (float)S[1];
  float az = w * (float)S[2], aw = w * (float)S[3];

  int beg = row_ptr[n], end = row_ptr[n + 1];
  int i = beg;
  for (; i + 8 <= end; i += 8) {
    int s0 = __builtin_amdgcn_readfirstlane(csr_src[i]);
    int s1 = __builtin_amdgcn_readfirstlane(csr_src[i + 1]);
    int s2 = __builtin_amdgcn_readfirstlane(csr_src[i + 2]);
    int s3 = __builtin_amdgcn_readfirstlane(csr_src[i + 3]);
    int s4 = __builtin_amdgcn_readfirstlane(csr_src[i + 4]);
    int s5 = __builtin_amdgcn_readfirstlane(csr_src[i + 5]);
    int s6 = __builtin_amdgcn_readfirstlane(csr_src[i + 6]);
    int s7 = __builtin_amdgcn_readfirstlane(csr_src[i + 7]);
    half4v A0 = *reinterpret_cast<const half4v*>(xl + (size_t)s0 * 256 + lane * 4);
    half4v A1 = *reinterpret_cast<const half4v*>(xl + (size_t)s1 * 256 + lane * 4);
    half4v A2 = *reinterpret_cast<const half4v*>(xl + (size_t)s2 * 256 + lane * 4);
    half4v A3 = *reinterpret_cast<const half4v*>(xl + (size_t)s3 * 256 + lane * 4);
    half4v A4 = *reinterpret_cast<const half4v*>(xl + (size_t)s4 * 256 + lane * 4);
    half4v A5 = *reinterpret_cast<const half4v*>(xl + (size_t)s5 * 256 + lane * 4);
    half4v A6 = *reinterpret_cast<const half4v*>(xl + (size_t)s6 * 256 + lane * 4);
    half4v A7 = *reinterpret_cast<const half4v*>(xl + (size_t)s7 * 256 + lane * 4);
    f32x2 qa, qb, qc, qd;
    qa[0] = edge_score(A0, R, p0, p1, q0h, q1h);
    qa[1] = edge_score(A1, R, p0, p1, q0h, q1h);
    qb[0] = edge_score(A2, R, p0, p1, q0h, q1h);
    qb[1] = edge_score(A3, R, p0, p1, q0h, q1h);
    qc[0] = edge_score(A4, R, p0, p1, q0h, q1h);
    qc[1] = edge_score(A5, R, p0, p1, q0h, q1h);
    qd[0] = edge_score(A6, R, p0, p1, q0h, q1h);
    qd[1] = edge_score(A7, R, p0, p1, q0h, q1h);
#pragma unroll
    for (int o = 1; o <= 8; o <<= 1) {
      f32x2 ta, tb, tc, td;
      ta[0] = __shfl_xor(qa[0], o); ta[1] = __shfl_xor(qa[1], o);
      tb[0] = __shfl_xor(qb[0], o); tb[1] = __shfl_xor(qb[1], o);
      tc[0] = __shfl_xor(qc[0], o); tc[1] = __shfl_xor(qc[1], o);
      td[0] = __shfl_xor(qd[0], o); td[1] = __shfl_xor(qd[1], o);
      qa = qa + ta; qb = qb + tb; qc = qc + tc; qd = qd + td;
    }
    float w0 = fexp2(qa[0]), w1 = fexp2(qa[1]);
    float w2 = fexp2(qb[0]), w3 = fexp2(qb[1]);
    float w4 = fexp2(qc[0]), w5 = fexp2(qc[1]);
    float w6 = fexp2(qd[0]), w7 = fexp2(qd[1]);
    den += ((w0 + w1) + (w2 + w3)) + ((w4 + w5) + (w6 + w7));
    ax = fmaf(w0, (float)A0[0], ax); ax = fmaf(w1, (float)A1[0], ax);
    ax = fmaf(w2, (float)A2[0], ax); ax = fmaf(w3, (float)A3[0], ax);
    ax = fmaf(w4, (float)A4[0], ax); ax = fmaf(w5, (float)A5[0], ax);
    ax = fmaf(w6, (float)A6[0], ax); ax = fmaf(w7, (float)A7[0], ax);
    ay = fmaf(w0, (float)A0[1], ay); ay = fmaf(w1, (float)A1[1], ay);
    ay = fmaf(w2, (float)A2[1], ay); ay = fmaf(w3, (float)A3[1], ay);
    ay = fmaf(w4, (float)A4[1], ay); ay = fmaf(w5, (float)A5[1], ay);
    ay = fmaf(w6, (float)A6[1], ay); ay = fmaf(w7, (float)A7[1], ay);
    az = fmaf(w0, (float)A0[2], az); az = fmaf(w1, (float)A1[2], az);
    az = fmaf(w2, (float)A2[2], az); az = fmaf(w3, (float)A3[2], az);
    az = fmaf(w4, (float)A4[2], az); az = fmaf(w5, (float)A5[2], az);
    az = fmaf(w6, (float)A6[2], az); az = fmaf(w7, (float)A7[2], az);
    aw = fmaf(w0, (float)A0[3], aw); aw = fmaf(w1, (float)A1[3], aw);
    aw = fmaf(w2, (float)A2[3], aw); aw = fmaf(w3, (float)A3[3], aw);
    aw = fmaf(w4, (float)A4[3], aw); aw = fmaf(w5, (float)A5[3], aw);
    aw = fmaf(w6, (float)A6[3], aw); aw = fmaf(w7, (float)A7[3], aw);
  }
  for (; i + 4 <= end; i += 4) {
    int s0 = __builtin_amdgcn_readfirstlane(csr_src[i]);
    int s1 = __builtin_amdgcn_readfirstlane(csr_src[i + 1]);
    int s2 = __builtin_amdgcn_readfirstlane(csr_src[i + 2]);
    int s3 = __builtin_amdgcn_readfirstlane(csr_src[i + 3]);
    half4v A0 = *reinterpret_cast<const half4v*>(xl + (size_t)s0 * 256 + lane * 4);
    half4v A1 = *reinterpret_cast<const half4v*>(xl + (size_t)s1 * 256 + lane * 4);
    half4v A2 = *reinterpret_cast<const half4v*>(xl + (size_t)s2 * 256 + lane * 4);
    half4v A3 = *reinterpret_cast<const half4v*>(xl + (size_t)s3 * 256 + lane * 4);
    f32x2 qa, qb;
    qa[0] = edge_score(A0, R, p0, p1, q0h, q1h);
    qa[1] = edge_score(A1, R, p0, p1, q0h, q1h);
    qb[0] = edge_score(A2, R, p0, p1, q0h, q1h);
    qb[1] = edge_score(A3, R, p0, p1, q0h, q1h);
#pragma unroll
    for (int o = 1; o <= 8; o <<= 1) {
      f32x2 ta, tb;
      ta[0] = __shfl_xor(qa[0], o); ta[1] = __shfl_xor(qa[1], o);
      tb[0] = __shfl_xor(qb[0], o); tb[1] = __shfl_xor(qb[1], o);
      qa = qa + ta; qb = qb + tb;
    }
    float w0 = fexp2(qa[0]), w1 = fexp2(qa[1]);
    float w2 = fexp2(qb[0]), w3 = fexp2(qb[1]);
    den += (w0 + w1) + (w2 + w3);
    ax = fmaf(w0, (float)A0[0], ax); ax = fmaf(w1, (float)A1[0], ax);
    ax = fmaf(w2, (float)A2[0], ax); ax = fmaf(w3, (float)A3[0], ax);
    ay = fmaf(w0, (float)A0[1], ay); ay = fmaf(w1, (float)A1[1], ay);
    ay = fmaf(w2, (float)A2[1], ay); ay = fmaf(w3, (float)A3[1], ay);
    az = fmaf(w0, (float)A0[2], az); az = fmaf(w1, (float)A1[2], az);
    az = fmaf(w2, (float)A2[2], az); az = fmaf(w3, (float)A3[2], az);
    aw = fmaf(w0, (float)A0[3], aw); aw = fmaf(w1, (float)A1[3], aw);
    aw = fmaf(w2, (float)A2[3], aw); aw = fmaf(w3, (float)A3[3], aw);
  }
  for (; i < end; ++i) {
    int s0 = __builtin_amdgcn_readfirstlane(csr_src[i]);
    half4v A0 = *reinterpret_cast<const half4v*>(xl + (size_t)s0 * 256 + lane * 4);
    q = reduce16(edge_score(A0, R, p0, p1, q0h, q1h));
    w = fexp2(q);
    den += w;
    ax = fmaf(w, (float)A0[0], ax); ay = fmaf(w, (float)A0[1], ay);
    az = fmaf(w, (float)A0[2], az); aw = fmaf(w, (float)A0[3], aw);
  }
  float inv = 1.f / den;
  ax *= inv; ay *= inv; az *= inv; aw *= inv;
  // mean over heads: lanes l, l^16, l^32, l^48 hold same feature of different heads
  ax += __shfl_xor(ax, 16); ay += __shfl_xor(ay, 16);
  az += __shfl_xor(az, 16); aw += __shfl_xor(aw, 16);
  ax += __shfl_xor(ax, 32); ay += __shfl_xor(ay, 32);
  az += __shfl_xor(az, 32); aw += __shfl_xor(aw, 32);
  // redistribute: feature `lane` = component (lane&3) of lane (lane>>2)
  int srcl = lane >> 2;
  float t0 = __shfl(ax, srcl), t1 = __shfl(ay, srcl);
  float t2 = __shfl(az, srcl), t3 = __shfl(aw, srcl);
  int r = lane & 3;
  float mean = (r == 0) ? t0 : (r == 1) ? t1 : (r == 2) ? t2 : t3;
  float val = mean * 0.25f + gat_b[lane];
  float mu = wsum(val) * (1.f / HID);
  float dv = val - mu;
  float var = wsum(dv * dv) * (1.f / HID);
  float h = dv * rsqrtf(var + 1e-5f) * g[lane] + bb[lane];
  h = h > 0.f ? h : 0.f;
  float outv = h + __half2float(h_init16[(size_t)n * HID + lane]);
  h2_16[(size_t)n * HID + lane] = __float2half(outv);
}

// ---------------- SAGE stage 1: pull mean-gather (fp16 out, n in SGPR, 8x MLP) --
__global__ __launch_bounds__(256) void k_sage_gather(
    const int* __restrict__ row_ptr, const int* __restrict__ csr_src,
    const __half* __restrict__ h2_16, __half* __restrict__ nmean16) {
  int n = wave_node();
  int lane = threadIdx.x & 63;
  int beg = row_ptr[n], end = row_ptr[n + 1];
  float sum = 0.f, sum2 = 0.f;
  int i = beg;
  for (; i + 8 <= end; i += 8) {
    int s0 = __builtin_amdgcn_readfirstlane(csr_src[i]);
    int s1 = __builtin_amdgcn_readfirstlane(csr_src[i + 1]);
    int s2 = __builtin_amdgcn_readfirstlane(csr_src[i + 2]);
    int s3 = __builtin_amdgcn_readfirstlane(csr_src[i + 3]);
    int s4 = __builtin_amdgcn_readfirstlane(csr_src[i + 4]);
    int s5 = __builtin_amdgcn_readfirstlane(csr_src[i + 5]);
    int s6 = __builtin_amdgcn_readfirstlane(csr_src[i + 6]);
    int s7 = __builtin_amdgcn_readfirstlane(csr_src[i + 7]);
    float v0 = __half2float(h2_16[(size_t)s0 * HID + lane]);
    float v1 = __half2float(h2_16[(size_t)s1 * HID + lane]);
    float v2 = __half2float(h2_16[(size_t)s2 * HID + lane]);
    float v3 = __half2float(h2_16[(size_t)s3 * HID + lane]);
    float v4 = __half2float(h2_16[(size_t)s4 * HID + lane]);
    float v5 = __half2float(h2_16[(size_t)s5 * HID + lane]);
    float v6 = __half2float(h2_16[(size_t)s6 * HID + lane]);
    float v7 = __half2float(h2_16[(size_t)s7 * HID + lane]);
    sum  += (v0 + v1) + (v2 + v3);
    sum2 += (v4 + v5) + (v6 + v7);
  }
  for (; i + 4 <= end; i += 4) {
    int s0 = __builtin_amdgcn_readfirstlane(csr_src[i]);
    int s1 = __builtin_amdgcn_readfirstlane(csr_src[i + 1]);
    int s2 = __builtin_amdgcn_readfirstlane(csr_src[i + 2]);
    int s3 = __builtin_amdgcn_readfirstlane(csr_src[i + 3]);
    float v0 = __half2float(h2_16[(size_t)s0 * HID + lane]);
    float v1 = __half2float(h2_16[(size_t)s1 * HID + lane]);
    float v2 = __half2float(h2_16[(size_t)s2 * HID + lane]);
    float v3 = __half2float(h2_16[(size_t)s3 * HID + lane]);
    sum += (v0 + v1) + (v2 + v3);
  }
  for (; i < end; ++i) {
    int s = __builtin_amdgcn_readfirstlane(csr_src[i]);
    sum += __half2float(h2_16[(size_t)s * HID + lane]);
  }
  nmean16[(size_t)n * HID + lane] =
      __float2half((sum + sum2) / fmaxf((float)(end - beg), 1.f));
}

// ---------------- SAGE stage 2 + heads (fused): h3 never materialized ----------
__global__ __launch_bounds__(64) void k_sage_gemm_ln_heads(
    const __half* __restrict__ nmean16, const __half* __restrict__ h2_16,
    const __half* __restrict__ h_init16,
    const float* __restrict__ Wl, const float* __restrict__ Wr,
    const float* __restrict__ sage_bl, const float* __restrict__ g,
    const float* __restrict__ bb, const int* __restrict__ mask,
    const float* __restrict__ mort_W, const float* __restrict__ mort_b,
    const float* __restrict__ hours_W, const float* __restrict__ hours_b,
    const float* __restrict__ disc_W, const float* __restrict__ disc_b,
    float* __restrict__ out) {
  __shared__ float nt[8][HID];
  __shared__ float ht[8][HID];
  int t = threadIdx.x;
  int n0 = blockIdx.x * 8;
  {
    const __half* np = nmean16 + (size_t)n0 * HID + t * 8;
    const __half* hp = h2_16 + (size_t)n0 * HID + t * 8;
    Half4 n0v = *reinterpret_cast<const Half4*>(np);
    Half4 n1v = *reinterpret_cast<const Half4*>(np + 4);
    Half4 p0 = *reinterpret_cast<const Half4*>(hp);
    Half4 p1 = *reinterpret_cast<const Half4*>(hp + 4);
    float* dn = &nt[0][0] + t * 8;
    float* dh = &ht[0][0] + t * 8;
    float2 f;
    f = __half22float2(n0v.a); dn[0] = f.x; dn[1] = f.y;
    f = __half22float2(n0v.b); dn[2] = f.x; dn[3] = f.y;
    f = __half22float2(n1v.a); dn[4] = f.x; dn[5] = f.y;
    f = __half22float2(n1v.b); dn[6] = f.x; dn[7] = f.y;
    f = __half22float2(p0.a);  dh[0] = f.x; dh[1] = f.y;
    f = __half22float2(p0.b);  dh[2] = f.x; dh[3] = f.y;
    f = __half22float2(p1.a);  dh[4] = f.x; dh[5] = f.y;
    f = __half22float2(p1.b);  dh[6] = f.x; dh[7] = f.y;
  }
  __syncthreads();
  int f = t;
  float acc[8] = {0.f,0.f,0.f,0.f,0.f,0.f,0.f,0.f};
  for (int k = 0; k < HID; k += 4) {
    float wl0 = Wl[(k + 0) * HID + f], wr0 = Wr[(k + 0) * HID + f];
    float wl1 = Wl[(k + 1) * HID + f], wr1 = Wr[(k + 1) * HID + f];
    float wl2 = Wl[(k + 2) * HID + f], wr2 = Wr[(k + 2) * HID + f];
    float wl3 = Wl[(k + 3) * HID + f], wr3 = Wr[(k + 3) * HID + f];
#pragma unroll
    for (int j = 0; j < 8; ++j) {
      float4 nv = *reinterpret_cast<const float4*>(&nt[j][k]);
      float4 hv = *reinterpret_cast<const float4*>(&ht[j][k]);
      acc[j] += nv.x * wl0 + nv.y * wl1 + nv.z * wl2 + nv.w * wl3
              + hv.x * wr0 + hv.y * wr1 + hv.z * wr2 + hv.w * wr3;
    }
  }
  float blv = sage_bl[f], gv = g[f], bbv = bb[f];
  float mw0 = mort_W[f], mw1 = mort_W[64 + f], mw2 = mort_W[128 + f];
  float hw0 = hours_W[f], hw1 = hours_W[64 + f], hw2 = hours_W[128 + f];
  float dwv[12];
#pragma unroll
  for (int rr = 0; rr < 3; ++rr)
#pragma unroll
    for (int c = 0; c < 4; ++c)
      dwv[rr * 4 + c] = disc_W[(rr * 64 + f) * 4 + c];
#pragma unroll
  for (int j = 0; j < 8; ++j) {
    float v = acc[j] + blv;
    float mu = wsum(v) * (1.f / HID);
    float dv = v - mu;
    float var = wsum(dv * dv) * (1.f / HID);
    float h = dv * rsqrtf(var + 1e-5f) * gv + bbv;
    h = h > 0.f ? h : 0.f;
    int n = n0 + j;
    float m = (mask[n] != 0) ? 1.f : 0.f;
    float v2 = (h + ht[j][f]) * m;                        // h3
    float v1 = ht[j][f] * m;                              // h2
    float v0 = __half2float(h_init16[(size_t)n * HID + f]) * m;
    float pm = v0 * mw0 + v1 * mw1 + v2 * mw2;
    float ph = v0 * hw0 + v1 * hw1 + v2 * hw2;
    float d0 = v0 * dwv[0] + v1 * dwv[4] + v2 * dwv[8];
    float d1 = v0 * dwv[1] + v1 * dwv[5] + v2 * dwv[9];
    float d2 = v0 * dwv[2] + v1 * dwv[6] + v2 * dwv[10];
    float d3 = v0 * dwv[3] + v1 * dwv[7] + v2 * dwv[11];
    pm = wsum(pm); ph = wsum(ph);
    d0 = wsum(d0); d1 = wsum(d1); d2 = wsum(d2); d3 = wsum(d3);
    if (f == 0) {
      out[n] = pm + mort_b[0];
      out[N_NODES + n] = ph + hours_b[0];
      float* dd = out + 2 * N_NODES + (size_t)n * 4;
      dd[0] = d0 + disc_b[0];
      dd[1] = d1 + disc_b[1];
      dd[2] = d2 + disc_b[2];
      dd[3] = d3 + disc_b[3];
    }
  }
}

extern "C" void kernel_launch(void* const* d_in, const int* in_sizes, int n_in,
                              void* d_out, int out_size, void* d_ws, size_t ws_size,
                              hipStream_t stream) {
  const float* x       = (const float*)d_in[0];
  const int*   ei      = (const int*)d_in[1];
  const float* ew      = (const float*)d_in[2];
  const int*   mask    = (const int*)d_in[3];
  const float* gcn_W   = (const float*)d_in[4];
  const float* gcn_b   = (const float*)d_in[5];
  const float* proj_W  = (const float*)d_in[6];
  const float* proj_b  = (const float*)d_in[7];
  const float* ln1_g   = (const float*)d_in[8];
  const float* ln1_b   = (const float*)d_in[9];
  const float* gat_Wl  = (const float*)d_in[10];
  const float* gat_Wr  = (const float*)d_in[11];
  const float* gat_att = (const float*)d_in[12];
  const float* gat_b   = (const float*)d_in[13];
  const float* ln2_g   = (const float*)d_in[14];
  const float* ln2_b   = (const float*)d_in[15];
  const float* sage_Wl = (const float*)d_in[16];
  const float* sage_bl = (const float*)d_in[17];
  const float* sage_Wr = (const float*)d_in[18];
  const float* ln3_g   = (const float*)d_in[19];
  const float* ln3_b   = (const float*)d_in[20];
  // d_in[21..24]: edge-MLP params — output unused by the reference; skipped.
  const float* mort_W  = (const float*)d_in[25];
  const float* mort_b  = (const float*)d_in[26];
  const float* hours_W = (const float*)d_in[27];
  const float* hours_b = (const float*)d_in[28];
  const float* disc_W  = (const float*)d_in[29];
  const float* disc_b  = (const float*)d_in[30];

  const int* src = ei;
  const int* dst = ei + N_EDGES;
  float* out = (float*)d_out;

  // ---- workspace layout ----
  float* ws = (float*)d_ws;
  const size_t F = (size_t)N_NODES * HID;  // 6.4M floats
  __half* xp16  = (__half*)(ws + 2 * F);           // N*64 halfs
  __half* xl    = (__half*)(ws + 3 * F);           // N*256 halfs
  __half* xw16  = xl;                              // N*64 halfs, dead before xl written
  __half* nmean16 = (__half*)(ws + 3 * F);         // N*64 halfs, xl dead by SAGE
  __half* xr    = (__half*)(ws + 3 * F + (size_t)N_NODES * 128);
  __half* h2_16 = (__half*)(ws + 3 * F + (size_t)N_NODES * 256);
  __half* h_init16 = (__half*)(ws + 3 * F + (size_t)N_NODES * 288);
  float* tail   = ws + 3 * F + (size_t)N_NODES * 320;
  int*   csr_src = (int*)tail;           tail += N_EDGES;
  float* csr_w   = tail;                 tail += N_EDGES;
  int*   row_ptr = (int*)tail;           tail += N_NODES + 64;
  int*   cursor  = (int*)tail;           tail += N_NODES;
  int*   cnt     = (int*)tail;           tail += N_NODES;
  int*   partial = (int*)tail;           tail += N_NODES;
  int*   bsum    = (int*)tail;           tail += 128;
  float* dinv    = tail;

  const int GE = (N_EDGES + 255) / 256;
  const int GN = (N_NODES + 255) / 256;
  const int GB = N_NODES / (16 * GEMM_NT);  // 1250 blocks for MFMA GEMMs

  // --- CSR build (by dst) ---
  hipMemsetAsync(cnt, 0, N_NODES * sizeof(int), stream);
  k_hist<<<GE, 256, 0, stream>>>(dst, cnt);
  k_scan1<<<SCAN_BLK, 256, 0, stream>>>(cnt, partial, bsum);
  k_scan3<<<GN, 256, 0, stream>>>(partial, bsum, row_ptr, cursor);
  k_fill<<<GE, 256, 0, stream>>>(src, dst, ew, cursor, csr_src, csr_w);

  // --- GCN layer ---
  k_in_gemm_mfma<<<GB, 512, 0, stream>>>(x, gcn_W, proj_W, proj_b, xw16, xp16);
  k_deg<<<GN, 256, 0, stream>>>(row_ptr, csr_w, dinv);
  k_gcn_fused<<<N_NODES / 4, 256, 0, stream>>>(row_ptr, csr_src, csr_w, dinv, xw16,
                                               xp16, gcn_b, ln1_g, ln1_b, h_init16);

  // --- GATv2 layer ---
  k_gat_gemm_mfma<<<GB, 512, 0, stream>>>(h_init16, gat_Wl, gat_Wr, xl, xr);
  k_gat_fused<<<N_NODES / 4, 256, 0, stream>>>(row_ptr, csr_src, xl, xr, gat_att,
                                               gat_b, ln2_g, ln2_b, h_init16, h2_16);

  // --- SAGE layer + heads (fused) ---
  k_sage_gather<<<N_NODES / 4, 256, 0, stream>>>(row_ptr, csr_src, h2_16, nmean16);
  k_sage_gemm_ln_heads<<<N_NODES / 8, 64, 0, stream>>>(
      nmean16, h2_16, h_init16, sage_Wl, sage_Wr, sage_bl, ln3_g, ln3_b, mask,
      mort_W, mort_b, hours_W, hours_b, disc_W, disc_b, out);
}